// Round 1
// baseline (287.684 us; speedup 1.0000x reference)
//
#include <hip/hip_runtime.h>
#include <hip/hip_bf16.h>

typedef __bf16 bf16x8 __attribute__((ext_vector_type(8)));
typedef float  f32x4  __attribute__((ext_vector_type(4)));

#define MFMA16(a, b, c) __builtin_amdgcn_mfma_f32_16x16x32_bf16(a, b, c, 0, 0, 0)

__device__ __forceinline__ float lrelu(float v) { return fmaxf(v, 0.01f * v); }

// ---------------------------------------------------------------------------
// prep kernels
// ---------------------------------------------------------------------------

// w1s[f][h] = sum_i linear1_w[f][i][h]   (16384 elements)
__global__ void vg_w1s(const float* __restrict__ lw1, float* __restrict__ w1s) {
  int i = blockIdx.x * 256 + threadIdx.x;
  int f = i >> 6, h = i & 63;
  w1s[i] = lw1[f * 192 + h] + lw1[f * 192 + 64 + h] + lw1[f * 192 + 128 + h];
}

// W2T[f][n(16,pad)][k(64)] = bf16(linear2_w[f][k][n]) , n>=8 -> 0   (262144)
__global__ void vg_w2t(const float* __restrict__ lw2, __bf16* __restrict__ w2t) {
  int i = blockIdx.x * 256 + threadIdx.x;
  int f = i >> 10, n = (i >> 6) & 15, k = i & 63;
  float v = (n < 8) ? lw2[(f * 64 + k) * 8 + n] : 0.f;
  w2t[i] = (__bf16)v;
}

// embT[f][d(128)][k(32,pad)] = bf16(emb[f][k][d]) , k>=8 -> 0   (1048576)
__global__ void vg_embt(const float* __restrict__ emb, __bf16* __restrict__ embt) {
  int i = blockIdx.x * 256 + threadIdx.x;
  int f = i >> 12, d = (i >> 5) & 127, k = i & 31;
  float v = (k < 8) ? emb[(f * 8 + k) * 128 + d] : 0.f;
  embt[i] = (__bf16)v;
}

// transpose [R][C] f32 -> [C][R] bf16, 64x64 LDS tiles
__global__ void vg_transpose(const float* __restrict__ in, __bf16* __restrict__ outT,
                             int R, int C) {
  __shared__ float tile[64][65];
  int tilesPerRow = C >> 6;
  int tr = blockIdx.x / tilesPerRow, tc = blockIdx.x % tilesPerRow;
  int r0 = tr * 64, c0 = tc * 64;
  int t = threadIdx.x;
  int cc = t & 63, rq = t >> 6;
#pragma unroll 4
  for (int i = 0; i < 16; i++) {
    int rr = rq * 16 + i;
    tile[rr][cc] = in[(size_t)(r0 + rr) * C + c0 + cc];
  }
  __syncthreads();
  int rr2 = t & 63, cq = t >> 6;
#pragma unroll 4
  for (int i = 0; i < 16; i++) {
    int cc2 = cq * 16 + i;
    outT[(size_t)(c0 + cc2) * R + r0 + rr2] = (__bf16)tile[rr2][cc2];
  }
}

// ---------------------------------------------------------------------------
// main fused kernel: per block = 128 rows x one f-group (32 f's)
// produces zpart[g][4096][256] f32
// ---------------------------------------------------------------------------
__global__ __launch_bounds__(512, 2) void vg_main(
    const float* __restrict__ x,      // [4096][256]
    const float* __restrict__ w1s,    // [256][64]
    const float* __restrict__ b1,     // [256][64]
    const __bf16* __restrict__ w2t,   // [256][16][64]
    const float* __restrict__ b2l,    // [256][8]
    const float* __restrict__ tau,    // [256][8]
    const __bf16* __restrict__ embt,  // [256][128][32]
    const __bf16* __restrict__ w1t,   // [256][32768]  (W1T[n][k])
    float* __restrict__ zpart)        // [8][4096][256]
{
  __shared__ __align__(16) float xs[128][33];
  __shared__ __align__(16) __bf16 elds[128 * 128];  // XOR-swizzled
  __shared__ __align__(16) __bf16 plds[128 * 32];   // linear, cols 8..31 stay 0

  const int g = blockIdx.x & 7;
  const int btile = blockIdx.x >> 3;
  const int r0 = btile * 128;
  const int f0 = g * 32;
  const int t = threadIdx.x;
  const int w = t >> 6, l = t & 63, lo = l & 15, hi = l >> 4;
  const int wm = w >> 2, wn = w & 3;  // big-gemm wave grid 2M x 4N

  // load + sanitize x tile [128][32]
#pragma unroll
  for (int i = 0; i < 8; i++) {
    int idx = i * 512 + t;
    int rr = idx >> 5, cc = idx & 31;
    float v = x[(size_t)(r0 + rr) * 256 + f0 + cc];
    v = (v != v) ? 0.f : v;
    xs[rr][cc] = fminf(fmaxf(v, 0.f), 65536.f);
  }
  for (int i = t; i < 128 * 32; i += 512) plds[i] = (__bf16)0.f;
  __syncthreads();

  f32x4 acc[4][4] = {};

  for (int fi = 0; fi < 32; fi++) {
    const int f = f0 + fi;

    // ---- phase 1: h A-fragments in registers (row = w*16+lo, k = s*32+hi*8+j)
    const float xr = xs[w * 16 + lo][fi];
    bf16x8 ha[2];
#pragma unroll
    for (int s = 0; s < 2; s++) {
      const float4* wp = (const float4*)(w1s + f * 64 + s * 32 + hi * 8);
      const float4* bp = (const float4*)(b1 + f * 64 + s * 32 + hi * 8);
      float4 wa = wp[0], wb = wp[1];
      float4 ba = bp[0], bb = bp[1];
      float hv[8];
      hv[0] = lrelu(xr * wa.x + ba.x);
      hv[1] = lrelu(xr * wa.y + ba.y);
      hv[2] = lrelu(xr * wa.z + ba.z);
      hv[3] = lrelu(xr * wa.w + ba.w);
      hv[4] = lrelu(xr * wb.x + bb.x);
      hv[5] = lrelu(xr * wb.y + bb.y);
      hv[6] = lrelu(xr * wb.z + bb.z);
      hv[7] = lrelu(xr * wb.w + bb.w);
#pragma unroll
      for (int i = 0; i < 8; i++) ha[s][i] = (__bf16)hv[i];
    }

    // ---- phase 2: g = h @ W2f  (M=16/wave, N=16 pad, K=64) + softmax
    f32x4 gacc = {0.f, 0.f, 0.f, 0.f};
#pragma unroll
    for (int s = 0; s < 2; s++) {
      bf16x8 bw = *(const bf16x8*)&w2t[(f * 16 + lo) * 64 + s * 32 + hi * 8];
      gacc = MFMA16(ha[s], bw, gacc);
    }
    const float b2v = (lo < 8) ? b2l[f * 8 + lo] : 0.f;
    const float tv = (lo < 8) ? tau[f * 8 + lo] : 1.f;
    float pv[4];
#pragma unroll
    for (int r = 0; r < 4; r++) {
      float gv = lrelu(gacc[r] + b2v) * tv;
      float mx = gv;
      mx = fmaxf(mx, __shfl_xor(mx, 1));
      mx = fmaxf(mx, __shfl_xor(mx, 2));
      mx = fmaxf(mx, __shfl_xor(mx, 4));
      float ev = __expf(gv - mx);
      float sm = ev;
      sm += __shfl_xor(sm, 1);
      sm += __shfl_xor(sm, 2);
      sm += __shfl_xor(sm, 4);
      pv[r] = ev * __builtin_amdgcn_rcpf(sm);
    }
    if (lo < 8) {
#pragma unroll
      for (int r = 0; r < 4; r++)
        plds[(w * 16 + hi * 4 + r) * 32 + lo] = (__bf16)pv[r];
    }
    __syncthreads();  // p visible; prev-iter elds reads done

    // ---- phase 3: e = p @ embT  (M=16/wave, N=128, K=32 pad)
    bf16x8 pa = *(const bf16x8*)&plds[(w * 16 + lo) * 32 + hi * 8];
    f32x4 ef[8];
#pragma unroll
    for (int d = 0; d < 8; d++) {
      bf16x8 eb = *(const bf16x8*)&embt[((size_t)f * 128 + d * 16 + lo) * 32 + hi * 8];
      f32x4 cz = {0.f, 0.f, 0.f, 0.f};
      ef[d] = MFMA16(pa, eb, cz);
    }
#pragma unroll
    for (int d = 0; d < 8; d++) {
#pragma unroll
      for (int r = 0; r < 4; r++) {
        int row = w * 16 + hi * 4 + r;
        int col = d * 16 + lo;
        elds[row * 128 + (col ^ ((row & 7) << 3))] = (__bf16)ef[d][r];
      }
    }
    __syncthreads();  // e-tile ready

    // ---- phase 4: z += e_tile @ W1T_f  (block M=128, N=256, K=128)
#pragma unroll
    for (int ks = 0; ks < 4; ks++) {
      bf16x8 A[4], Bq[4];
#pragma unroll
      for (int m = 0; m < 4; m++) {
        int row = wm * 64 + m * 16 + lo;
        A[m] = *(const bf16x8*)&elds[row * 128 + ((ks * 32 + hi * 8) ^ ((row & 7) << 3))];
      }
#pragma unroll
      for (int n = 0; n < 4; n++) {
        int col = wn * 64 + n * 16 + lo;
        Bq[n] = *(const bf16x8*)&w1t[(size_t)col * 32768 + f * 128 + ks * 32 + hi * 8];
      }
#pragma unroll
      for (int m = 0; m < 4; m++)
#pragma unroll
        for (int n = 0; n < 4; n++) acc[m][n] = MFMA16(A[m], Bq[n], acc[m][n]);
    }
  }

  float* zp = zpart + (size_t)g * (4096 * 256) + (size_t)r0 * 256;
#pragma unroll
  for (int m = 0; m < 4; m++)
#pragma unroll
    for (int n = 0; n < 4; n++)
#pragma unroll
      for (int r = 0; r < 4; r++) {
        int row = wm * 64 + m * 16 + hi * 4 + r;
        int col = wn * 64 + n * 16 + lo;
        zp[row * 256 + col] = acc[m][n][r];
      }
}

// ---------------------------------------------------------------------------
// z[b][n] = bf16(relu(sum_g zpart + b1p[n]))
// ---------------------------------------------------------------------------
__global__ void vg_zred(const float* __restrict__ zpart, const float* __restrict__ b1p,
                        __bf16* __restrict__ z) {
  int i = blockIdx.x * 256 + threadIdx.x;  // 1048576
  float s = b1p[i & 255];
#pragma unroll
  for (int g = 0; g < 8; g++) s += zpart[(size_t)g * 1048576 + i];
  z[i] = (__bf16)fmaxf(s, 0.f);
}

// ---------------------------------------------------------------------------
// out = z @ W2 + b2   (M=4096, N=4096, K=256)
// ---------------------------------------------------------------------------
__global__ __launch_bounds__(256, 2) void vg_out(
    const __bf16* __restrict__ z,    // [4096][256]
    const __bf16* __restrict__ w2t,  // [4096][256]  (W2T[n][k])
    const float* __restrict__ b2,    // [4096]
    float* __restrict__ out)         // [4096][4096]
{
  const int m0 = (blockIdx.x & 31) * 128;
  const int n0 = (blockIdx.x >> 5) * 128;
  const int t = threadIdx.x, w = t >> 6, l = t & 63, lo = l & 15, hi = l >> 4;
  const int wm = w >> 1, wn = w & 1;  // 2x2 waves, 64x64 each
  f32x4 acc[4][4] = {};
#pragma unroll
  for (int ks = 0; ks < 8; ks++) {
    bf16x8 A[4], Bq[4];
#pragma unroll
    for (int m = 0; m < 4; m++)
      A[m] = *(const bf16x8*)&z[(size_t)(m0 + wm * 64 + m * 16 + lo) * 256 + ks * 32 + hi * 8];
#pragma unroll
    for (int n = 0; n < 4; n++)
      Bq[n] = *(const bf16x8*)&w2t[(size_t)(n0 + wn * 64 + n * 16 + lo) * 256 + ks * 32 + hi * 8];
#pragma unroll
    for (int m = 0; m < 4; m++)
#pragma unroll
      for (int n = 0; n < 4; n++) acc[m][n] = MFMA16(A[m], Bq[n], acc[m][n]);
  }
#pragma unroll
  for (int m = 0; m < 4; m++)
#pragma unroll
    for (int n = 0; n < 4; n++) {
      int col = n0 + wn * 64 + n * 16 + lo;
      float bv = b2[col];
#pragma unroll
      for (int r = 0; r < 4; r++) {
        int row = m0 + wm * 64 + m * 16 + hi * 4 + r;
        out[(size_t)row * 4096 + col] = acc[m][n][r] + bv;
      }
    }
}

// ---------------------------------------------------------------------------
extern "C" void kernel_launch(void* const* d_in, const int* in_sizes, int n_in,
                              void* d_out, int out_size, void* d_ws, size_t ws_size,
                              hipStream_t stream) {
  const float* x   = (const float*)d_in[0];
  const float* lw1 = (const float*)d_in[1];
  const float* b1  = (const float*)d_in[2];
  const float* lw2 = (const float*)d_in[3];
  const float* b2l = (const float*)d_in[4];
  const float* tau = (const float*)d_in[5];
  const float* emb = (const float*)d_in[6];
  const float* pw1 = (const float*)d_in[7];
  const float* pb1 = (const float*)d_in[8];
  const float* pw2 = (const float*)d_in[9];
  const float* pb2 = (const float*)d_in[10];
  float* out = (float*)d_out;

  char* ws = (char*)d_ws;
  float*  w1s  = (float*)(ws + 0);          //      65536 B
  __bf16* w2t  = (__bf16*)(ws + 65536);     //     524288 B
  __bf16* embt = (__bf16*)(ws + 589824);    //    2097152 B
  __bf16* w1t  = (__bf16*)(ws + 2686976);   //   16777216 B
  __bf16* w2t3 = (__bf16*)(ws + 19464192);  //    2097152 B
  __bf16* z    = (__bf16*)(ws + 21561344);  //    2097152 B
  float*  zpart = (float*)(ws + 23658496);  //   33554432 B  (total 57212928)

  vg_w1s<<<64, 256, 0, stream>>>(lw1, w1s);
  vg_w2t<<<1024, 256, 0, stream>>>(lw2, w2t);
  vg_embt<<<4096, 256, 0, stream>>>(emb, embt);
  vg_transpose<<<2048, 256, 0, stream>>>(pw1, w1t, 32768, 256);
  vg_transpose<<<256, 256, 0, stream>>>(pw2, w2t3, 256, 4096);
  vg_main<<<256, 512, 0, stream>>>(x, w1s, b1, w2t, b2l, tau, embt, w1t, zpart);
  vg_zred<<<4096, 256, 0, stream>>>(zpart, pb1, z);
  vg_out<<<1024, 256, 0, stream>>>(z, w2t3, pb2, out);
}

// Round 2
// 221.522 us; speedup vs baseline: 1.2987x; 1.2987x over previous
//
#include <hip/hip_runtime.h>
#include <hip/hip_bf16.h>

typedef __bf16 bf16x8 __attribute__((ext_vector_type(8)));
typedef float  f32x4  __attribute__((ext_vector_type(4)));

#define MFMA16(a, b, c) __builtin_amdgcn_mfma_f32_16x16x32_bf16(a, b, c, 0, 0, 0)

__device__ __forceinline__ float lrelu(float v) { return fmaxf(v, 0.01f * v); }

// ---------------------------------------------------------------------------
// prep kernels
// ---------------------------------------------------------------------------

// w1s[f][h] = sum_i linear1_w[f][i][h]   (16384 elements)
__global__ void vg_w1s(const float* __restrict__ lw1, float* __restrict__ w1s) {
  int i = blockIdx.x * 256 + threadIdx.x;
  int f = i >> 6, h = i & 63;
  w1s[i] = lw1[f * 192 + h] + lw1[f * 192 + 64 + h] + lw1[f * 192 + 128 + h];
}

// W2T[f][n(16,pad)][k(64)] = bf16(linear2_w[f][k][n]) , n>=8 -> 0   (262144)
__global__ void vg_w2t(const float* __restrict__ lw2, __bf16* __restrict__ w2t) {
  int i = blockIdx.x * 256 + threadIdx.x;
  int f = i >> 10, n = (i >> 6) & 15, k = i & 63;
  float v = (n < 8) ? lw2[(f * 64 + k) * 8 + n] : 0.f;
  w2t[i] = (__bf16)v;
}

// embT[f][d(128)][k(32,pad)] = bf16(emb[f][k][d]) , k>=8 -> 0   (1048576)
__global__ void vg_embt(const float* __restrict__ emb, __bf16* __restrict__ embt) {
  int i = blockIdx.x * 256 + threadIdx.x;
  int f = i >> 12, d = (i >> 5) & 127, k = i & 31;
  float v = (k < 8) ? emb[(f * 8 + k) * 128 + d] : 0.f;
  embt[i] = (__bf16)v;
}

// w1tf[f][n(256)][k(128)] = bf16(pw1[(f*128+k)*256 + n])  -- per-f contiguous
__global__ void vg_w1tf(const float* __restrict__ pw1, __bf16* __restrict__ w1tf) {
  __shared__ __bf16 tl[128][258];
  const int f = blockIdx.x, t = threadIdx.x;
  const float* src = pw1 + (size_t)f * 32768;
  for (int idx = t; idx < 32768; idx += 256) {
    int k = idx >> 8, n = idx & 255;
    tl[k][n] = (__bf16)src[idx];
  }
  __syncthreads();
  __bf16* dst = w1tf + (size_t)f * 32768;
  for (int idx = t; idx < 32768; idx += 256) {
    int n = idx >> 7, k = idx & 127;
    dst[idx] = tl[k][n];
  }
}

// transpose [R][C] f32 -> [C][R] bf16, 64x64 LDS tiles (for proj_w2)
__global__ void vg_transpose(const float* __restrict__ in, __bf16* __restrict__ outT,
                             int R, int C) {
  __shared__ float tile[64][65];
  int tilesPerRow = C >> 6;
  int tr = blockIdx.x / tilesPerRow, tc = blockIdx.x % tilesPerRow;
  int r0 = tr * 64, c0 = tc * 64;
  int t = threadIdx.x;
  int cc = t & 63, rq = t >> 6;
#pragma unroll 4
  for (int i = 0; i < 16; i++) {
    int rr = rq * 16 + i;
    tile[rr][cc] = in[(size_t)(r0 + rr) * C + c0 + cc];
  }
  __syncthreads();
  int rr2 = t & 63, cq = t >> 6;
#pragma unroll 4
  for (int i = 0; i < 16; i++) {
    int cc2 = cq * 16 + i;
    outT[(size_t)(c0 + cc2) * R + r0 + rr2] = (__bf16)tile[rr2][cc2];
  }
}

// ---------------------------------------------------------------------------
// main fused kernel: per block = 128 rows x one f-group (32 f's)
// produces zpart[g][4096][256] f32
// ---------------------------------------------------------------------------
__global__ __launch_bounds__(512, 2) void vg_main(
    const float* __restrict__ x,      // [4096][256]
    const float* __restrict__ w1s,    // [256][64]
    const float* __restrict__ b1,     // [256][64]
    const __bf16* __restrict__ w2t,   // [256][16][64]
    const float* __restrict__ b2l,    // [256][8]
    const float* __restrict__ tau,    // [256][8]
    const __bf16* __restrict__ embt,  // [256][128][32]
    const __bf16* __restrict__ w1tf,  // [256][256][128]
    float* __restrict__ zpart)        // [8][4096][256]
{
  __shared__ __align__(16) __bf16 elds[2][128 * 128];  // XOR-swizzled, dbuf
  __shared__ __align__(16) __bf16 plds[128 * 40];      // stride-40, cols 8..39 zero
  __shared__ __align__(16) float xs[128][33];
  __shared__ __align__(16) float ws1[2048], wb1[2048];
  __shared__ __align__(16) float wb2[256], wtau[256];

  const int g = blockIdx.x & 7;
  const int r0 = (blockIdx.x >> 3) * 128;
  const int f0 = g * 32;
  const int t = threadIdx.x;
  const int w = t >> 6, l = t & 63, lo = l & 15, hi = l >> 4;

  // load + sanitize x tile [128][32]
#pragma unroll
  for (int i = 0; i < 8; i++) {
    int idx = i * 512 + t;
    int rr = idx >> 5, cc = idx & 31;
    float v = x[(size_t)(r0 + rr) * 256 + f0 + cc];
    v = (v != v) ? 0.f : v;
    xs[rr][cc] = fminf(fmaxf(v, 0.f), 65536.f);
  }
  // preload per-f small params into LDS
  for (int i = t; i < 2048; i += 512) {
    ws1[i] = w1s[f0 * 64 + i];
    wb1[i] = b1[f0 * 64 + i];
  }
  if (t < 256) {
    wb2[t] = b2l[f0 * 8 + t];
    wtau[t] = tau[f0 * 8 + t];
  }
  for (int i = t; i < 128 * 40; i += 512) plds[i] = (__bf16)0.f;
  __syncthreads();

  f32x4 acc[8][2] = {};

  for (int fi = 0; fi < 32; fi++) {
    const int f = f0 + fi;
    __bf16* eb_ = &elds[fi & 1][0];

    // ---- issue phase-4 B loads EARLY (latency hidden by phases 1-3)
    bf16x8 Bq[4][2];
    {
      const __bf16* bp = w1tf + ((size_t)f * 256 + w * 32) * 128;
#pragma unroll
      for (int ks = 0; ks < 4; ks++)
#pragma unroll
        for (int n = 0; n < 2; n++)
          Bq[ks][n] = *(const bf16x8*)&bp[(n * 16 + lo) * 128 + ks * 32 + hi * 8];
    }

    // ---- phase 1: h A-fragments (row = w*16+lo, k = s*32+hi*8+j)
    const float xr = xs[w * 16 + lo][fi];
    bf16x8 ha[2];
#pragma unroll
    for (int s = 0; s < 2; s++) {
      const float4* wp = (const float4*)(ws1 + fi * 64 + s * 32 + hi * 8);
      const float4* bp2 = (const float4*)(wb1 + fi * 64 + s * 32 + hi * 8);
      float4 wa = wp[0], wb = wp[1];
      float4 ba = bp2[0], bb = bp2[1];
      float hv[8];
      hv[0] = lrelu(xr * wa.x + ba.x);
      hv[1] = lrelu(xr * wa.y + ba.y);
      hv[2] = lrelu(xr * wa.z + ba.z);
      hv[3] = lrelu(xr * wa.w + ba.w);
      hv[4] = lrelu(xr * wb.x + bb.x);
      hv[5] = lrelu(xr * wb.y + bb.y);
      hv[6] = lrelu(xr * wb.z + bb.z);
      hv[7] = lrelu(xr * wb.w + bb.w);
#pragma unroll
      for (int i = 0; i < 8; i++) ha[s][i] = (__bf16)hv[i];
    }

    // ---- phase 2: g = h @ W2f (M=16, N=16 pad, K=64) + softmax (8 buckets in lo 0..7)
    f32x4 gacc = {0.f, 0.f, 0.f, 0.f};
#pragma unroll
    for (int s = 0; s < 2; s++) {
      bf16x8 bw = *(const bf16x8*)&w2t[(f * 16 + lo) * 64 + s * 32 + hi * 8];
      gacc = MFMA16(ha[s], bw, gacc);
    }
    const float b2v = (lo < 8) ? wb2[fi * 8 + lo] : 0.f;
    const float tv = (lo < 8) ? wtau[fi * 8 + lo] : 1.f;
    float pv[4];
#pragma unroll
    for (int r = 0; r < 4; r++) {
      float gv = lrelu(gacc[r] + b2v) * tv;
      float mx = gv;
      mx = fmaxf(mx, __shfl_xor(mx, 1));
      mx = fmaxf(mx, __shfl_xor(mx, 2));
      mx = fmaxf(mx, __shfl_xor(mx, 4));
      float ev = __expf(gv - mx);
      float sm = ev;
      sm += __shfl_xor(sm, 1);
      sm += __shfl_xor(sm, 2);
      sm += __shfl_xor(sm, 4);
      pv[r] = ev * __builtin_amdgcn_rcpf(sm);
    }
    if (lo < 8) {
#pragma unroll
      for (int r = 0; r < 4; r++)
        plds[(w * 16 + hi * 4 + r) * 40 + lo] = (__bf16)pv[r];
    }
    // plds region is wave-private: no __syncthreads needed, just drain DS queue
    asm volatile("s_waitcnt lgkmcnt(0)" ::: "memory");
    __builtin_amdgcn_sched_barrier(0);

    // ---- phase 3: e = p @ embT (M=16, N=128, K=32 pad)
    bf16x8 pa = *(const bf16x8*)&plds[(w * 16 + lo) * 40 + hi * 8];
    f32x4 ef[8];
#pragma unroll
    for (int d = 0; d < 8; d++) {
      bf16x8 ebg = *(const bf16x8*)&embt[((size_t)f * 128 + d * 16 + lo) * 32 + hi * 8];
      f32x4 cz = {0.f, 0.f, 0.f, 0.f};
      ef[d] = MFMA16(pa, ebg, cz);
    }
#pragma unroll
    for (int d = 0; d < 8; d++) {
#pragma unroll
      for (int r = 0; r < 4; r++) {
        int row = w * 16 + hi * 4 + r;
        int col = d * 16 + lo;
        eb_[row * 128 + (col ^ ((row & 7) << 3))] = (__bf16)ef[d][r];
      }
    }
    __syncthreads();  // e-tile ready (dbuf handles WAR across iterations)

    // ---- phase 4: z += e_tile @ W1T_f  (wave = all 128 rows x 32 cols)
#pragma unroll
    for (int ks = 0; ks < 4; ks++) {
      bf16x8 A[8];
#pragma unroll
      for (int m = 0; m < 8; m++) {
        int row = m * 16 + lo;
        A[m] = *(const bf16x8*)&eb_[row * 128 + ((ks * 32 + hi * 8) ^ ((row & 7) << 3))];
      }
#pragma unroll
      for (int m = 0; m < 8; m++)
#pragma unroll
        for (int n = 0; n < 2; n++) acc[m][n] = MFMA16(A[m], Bq[ks][n], acc[m][n]);
    }
  }

  float* zp = zpart + (size_t)g * (4096 * 256) + (size_t)r0 * 256;
#pragma unroll
  for (int m = 0; m < 8; m++)
#pragma unroll
    for (int n = 0; n < 2; n++)
#pragma unroll
      for (int r = 0; r < 4; r++) {
        int row = m * 16 + hi * 4 + r;
        int col = w * 32 + n * 16 + lo;
        zp[row * 256 + col] = acc[m][n][r];
      }
}

// ---------------------------------------------------------------------------
// z[b][n] = bf16(relu(sum_g zpart + b1p[n]))
// ---------------------------------------------------------------------------
__global__ void vg_zred(const float* __restrict__ zpart, const float* __restrict__ b1p,
                        __bf16* __restrict__ z) {
  int i = blockIdx.x * 256 + threadIdx.x;  // 1048576
  float s = b1p[i & 255];
#pragma unroll
  for (int g = 0; g < 8; g++) s += zpart[(size_t)g * 1048576 + i];
  z[i] = (__bf16)fmaxf(s, 0.f);
}

// ---------------------------------------------------------------------------
// out = z @ W2 + b2   (M=4096, N=4096, K=256)
// ---------------------------------------------------------------------------
__global__ __launch_bounds__(256, 2) void vg_out(
    const __bf16* __restrict__ z,    // [4096][256]
    const __bf16* __restrict__ w2t,  // [4096][256]  (W2T[n][k])
    const float* __restrict__ b2,    // [4096]
    float* __restrict__ out)         // [4096][4096]
{
  const int m0 = (blockIdx.x & 31) * 128;
  const int n0 = (blockIdx.x >> 5) * 128;
  const int t = threadIdx.x, w = t >> 6, l = t & 63, lo = l & 15, hi = l >> 4;
  const int wm = w >> 1, wn = w & 1;  // 2x2 waves, 64x64 each
  f32x4 acc[4][4] = {};
#pragma unroll
  for (int ks = 0; ks < 8; ks++) {
    bf16x8 A[4], Bq[4];
#pragma unroll
    for (int m = 0; m < 4; m++)
      A[m] = *(const bf16x8*)&z[(size_t)(m0 + wm * 64 + m * 16 + lo) * 256 + ks * 32 + hi * 8];
#pragma unroll
    for (int n = 0; n < 4; n++)
      Bq[n] = *(const bf16x8*)&w2t[(size_t)(n0 + wn * 64 + n * 16 + lo) * 256 + ks * 32 + hi * 8];
#pragma unroll
    for (int m = 0; m < 4; m++)
#pragma unroll
      for (int n = 0; n < 4; n++) acc[m][n] = MFMA16(A[m], Bq[n], acc[m][n]);
  }
#pragma unroll
  for (int m = 0; m < 4; m++)
#pragma unroll
    for (int n = 0; n < 4; n++) {
      int col = n0 + wn * 64 + n * 16 + lo;
      float bv = b2[col];
#pragma unroll
      for (int r = 0; r < 4; r++) {
        int row = m0 + wm * 64 + m * 16 + hi * 4 + r;
        out[(size_t)row * 4096 + col] = acc[m][n][r] + bv;
      }
    }
}

// ---------------------------------------------------------------------------
extern "C" void kernel_launch(void* const* d_in, const int* in_sizes, int n_in,
                              void* d_out, int out_size, void* d_ws, size_t ws_size,
                              hipStream_t stream) {
  const float* x   = (const float*)d_in[0];
  const float* lw1 = (const float*)d_in[1];
  const float* b1  = (const float*)d_in[2];
  const float* lw2 = (const float*)d_in[3];
  const float* b2l = (const float*)d_in[4];
  const float* tau = (const float*)d_in[5];
  const float* emb = (const float*)d_in[6];
  const float* pw1 = (const float*)d_in[7];
  const float* pb1 = (const float*)d_in[8];
  const float* pw2 = (const float*)d_in[9];
  const float* pb2 = (const float*)d_in[10];
  float* out = (float*)d_out;

  char* ws = (char*)d_ws;
  float*  w1s  = (float*)(ws + 0);          //      65536 B
  __bf16* w2t  = (__bf16*)(ws + 65536);     //     524288 B
  __bf16* embt = (__bf16*)(ws + 589824);    //    2097152 B
  __bf16* w1tf = (__bf16*)(ws + 2686976);   //   16777216 B
  __bf16* w2t3 = (__bf16*)(ws + 19464192);  //    2097152 B
  __bf16* z    = (__bf16*)(ws + 21561344);  //    2097152 B
  float*  zpart = (float*)(ws + 23658496);  //   33554432 B  (total 57212928)

  vg_w1s<<<64, 256, 0, stream>>>(lw1, w1s);
  vg_w2t<<<1024, 256, 0, stream>>>(lw2, w2t);
  vg_embt<<<4096, 256, 0, stream>>>(emb, embt);
  vg_w1tf<<<256, 256, 0, stream>>>(pw1, w1tf);
  vg_transpose<<<256, 256, 0, stream>>>(pw2, w2t3, 256, 4096);
  vg_main<<<256, 512, 0, stream>>>(x, w1s, b1, w2t, b2l, tau, embt, w1tf, zpart);
  vg_zred<<<4096, 256, 0, stream>>>(zpart, pb1, z);
  vg_out<<<1024, 256, 0, stream>>>(z, w2t3, pb2, out);
}